// Round 6
// baseline (44.079 us; speedup 1.0000x reference)
//
#include <hip/hip_runtime.h>

// Gaussian3D single-node kernel: values (M,1) + weights (M,N). M=8192, N=4096.
// d_out layout: [values (M) | weights (M*N)], float32.
//
// Structure: 1024 blocks x 256 threads, MPB=8 rows/block, all blocks
// co-resident. Chunk-looped over N (4 chunks x 4 consecutive n per thread).
// Each chunk INLINE-folds its 4 gaussians' coefficients (quat->R->cov->
// inverse->expanded quadratic) in registers -- no precomp kernel, no
// workspace, no inter-kernel dependency bubble. Redundant VALU (~6 us,
// hides under the ~21 us HBM store drain).
//   arg(p) = A:pp + B.p + C,  weight = exp2(arg)   [v_exp_f32]
// Stores batched 4 rows deep (wbuf, static-indexed) -> 4 KB bursts/wave.
// values finish in-block: vs[8] -> batched shuffle reduce -> LDS combine.

#define THREADS 256
#define JPT 4
#define MPB 8
#define NN 4096
#define MM 8192
#define CHUNKS (NN / (THREADS * JPT))  // 4

typedef float f32x4 __attribute__((ext_vector_type(4)));

__global__ __launch_bounds__(THREADS, 3) void gauss_fused(
    const float* __restrict__ points,
    const float* __restrict__ xyz,
    const float* __restrict__ scale_raw,
    const float* __restrict__ rot_raw,
    const float* __restrict__ op_raw,
    const float* __restrict__ feat,
    float* __restrict__ values,
    float* __restrict__ weights) {
  const int t = threadIdx.x;
  const int mbase = blockIdx.x * MPB;
  const float k = -0.72134752044448170f;  // -0.5*log2(e)

  __shared__ float spts[MPB * 3];
  __shared__ float part[MPB][THREADS / 64];
  if (t < MPB * 3) spts[t] = points[mbase * 3 + t];
  __syncthreads();

  float vs[MPB];
#pragma unroll
  for (int i = 0; i < MPB; ++i) vs[i] = 0.f;

#pragma unroll
  for (int c = 0; c < CHUNKS; ++c) {
    const int n0 = c * (THREADS * JPT) + t * JPT;  // multiple of 4

    // ---- inline fold: coefficients for gaussians n0..n0+3 ----
    float A00[JPT], A11[JPT], A22[JPT], A01[JPT], A02[JPT], A12[JPT];
    float B0[JPT], B1[JPT], B2[JPT], CC[JPT], FF[JPT];
    {
      const float4* rot4 = (const float4*)(rot_raw + 4 * (size_t)n0);
      const float4 q0 = rot4[0], q1 = rot4[1], q2 = rot4[2], q3 = rot4[3];
      const float4* sc4 = (const float4*)(scale_raw + 3 * (size_t)n0);
      const float4 s0 = sc4[0], s1 = sc4[1], s2 = sc4[2];
      const float4* xy4 = (const float4*)(xyz + 3 * (size_t)n0);
      const float4 p0 = xy4[0], p1 = xy4[1], p2 = xy4[2];
      const float4 op4 = *(const float4*)(op_raw + n0);
      const float4 f4  = *(const float4*)(feat + n0);

      const float4 q[JPT] = {q0, q1, q2, q3};
      const float sxa[JPT] = {s0.x, s0.w, s1.z, s2.y};
      const float sya[JPT] = {s0.y, s1.x, s1.w, s2.z};
      const float sza[JPT] = {s0.z, s1.y, s2.x, s2.w};
      const float xxa[JPT] = {p0.x, p0.w, p1.z, p2.y};
      const float yya[JPT] = {p0.y, p1.x, p1.w, p2.z};
      const float zza[JPT] = {p0.z, p1.y, p2.x, p2.w};
      const float opa[JPT] = {op4.x, op4.y, op4.z, op4.w};
      const float fa[JPT]  = {f4.x, f4.y, f4.z, f4.w};

#pragma unroll
      for (int j = 0; j < JPT; ++j) {
        float qw = q[j].x, qx = q[j].y, qy = q[j].z, qz = q[j].w;
        const float inorm = rsqrtf(qw*qw + qx*qx + qy*qy + qz*qz);
        qw *= inorm; qx *= inorm; qy *= inorm; qz *= inorm;
        const float sx = __expf(sxa[j]);
        const float sy = __expf(sya[j]);
        const float sz = __expf(sza[j]);
        const float r00 = 1.f - 2.f*(qy*qy + qz*qz);
        const float r01 = 2.f*(qx*qy - qw*qz);
        const float r02 = 2.f*(qx*qz + qw*qy);
        const float r10 = 2.f*(qx*qy + qw*qz);
        const float r11 = 1.f - 2.f*(qx*qx + qz*qz);
        const float r12 = 2.f*(qy*qz - qw*qx);
        const float r20 = 2.f*(qx*qz - qw*qy);
        const float r21 = 2.f*(qy*qz + qw*qx);
        const float r22 = 1.f - 2.f*(qx*qx + qy*qy);
        const float a0 = r00*sx, a1 = r01*sy, a2 = r02*sz;
        const float b0_ = r10*sx, b1_ = r11*sy, b2_ = r12*sz;
        const float c0_ = r20*sx, c1_ = r21*sy, c2_ = r22*sz;
        const float c00 = a0*a0 + a1*a1 + a2*a2;
        const float c01 = a0*b0_ + a1*b1_ + a2*b2_;
        const float c02 = a0*c0_ + a1*c1_ + a2*c2_;
        const float c11 = b0_*b0_ + b1_*b1_ + b2_*b2_;
        const float c12 = b0_*c0_ + b1_*c1_ + b2_*c2_;
        const float c22 = c0_*c0_ + c1_*c1_ + c2_*c2_;
        const float m00 = c11*c22 - c12*c12;
        const float m01 = c02*c12 - c01*c22;
        const float m02 = c01*c12 - c02*c11;
        const float det = c00*m00 + c01*m01 + c02*m02;
        const float idet = 1.f / det;
        const float i00 = m00*idet;
        const float i01 = m01*idet;
        const float i02 = m02*idet;
        const float i11 = (c00*c22 - c02*c02)*idet;
        const float i12 = (c02*c01 - c00*c12)*idet;
        const float i22 = (c00*c11 - c01*c01)*idet;
        const float gx = xxa[j], gy = yya[j], gz = zza[j];
        const float w0 = i00*gx + i01*gy + i02*gz;
        const float w1 = i01*gx + i11*gy + i12*gz;
        const float w2 = i02*gx + i12*gy + i22*gz;
        A00[j] = k * i00;
        A11[j] = k * i11;
        A22[j] = k * i22;
        A01[j] = 2.f * k * i01;
        A02[j] = 2.f * k * i02;
        A12[j] = 2.f * k * i12;
        B0[j] = -2.f * k * w0;
        B1[j] = -2.f * k * w1;
        B2[j] = -2.f * k * w2;
        const float gIg = gx*w0 + gy*w1 + gz*w2;
        const float lop = -__log2f(1.f + __expf(-opa[j]));  // log2(sigmoid)
        CC[j] = k * gIg + lop;
        FF[j] = fa[j];
      }
    }

    // ---- sweep 8 rows; stores batched 4 rows deep ----
    f32x4 wbuf[4];
#pragma unroll
    for (int i = 0; i < MPB; ++i) {
      const float px = spts[3*i+0];
      const float py = spts[3*i+1];
      const float pz = spts[3*i+2];
      const float pxx = px*px, pyy = py*py, pzz = pz*pz;
      const float pxy = px*py, pxz = px*pz, pyz = py*pz;
      f32x4 w;
      float vsum = vs[i];
#pragma unroll
      for (int j = 0; j < JPT; ++j) {
        float arg = CC[j];
        arg = fmaf(B2[j], pz, arg);
        arg = fmaf(B1[j], py, arg);
        arg = fmaf(B0[j], px, arg);
        arg = fmaf(A12[j], pyz, arg);
        arg = fmaf(A02[j], pxz, arg);
        arg = fmaf(A01[j], pxy, arg);
        arg = fmaf(A22[j], pzz, arg);
        arg = fmaf(A11[j], pyy, arg);
        arg = fmaf(A00[j], pxx, arg);
        const float wj = __builtin_amdgcn_exp2f(arg);
        w[j] = wj;
        vsum = fmaf(wj, FF[j], vsum);
      }
      vs[i] = vsum;
      wbuf[i & 3] = w;  // static index (i unrolled)
      if ((i & 3) == 3) {
#pragma unroll
        for (int b = 0; b < 4; ++b) {
          *(f32x4*)&weights[(size_t)(mbase + (i - 3 + b)) * NN + n0] = wbuf[b];
        }
      }
    }
  }

  // batched wave reduction: MPB independent 6-stage chains
#pragma unroll
  for (int i = 0; i < MPB; ++i) {
#pragma unroll
    for (int off = 32; off >= 1; off >>= 1)
      vs[i] += __shfl_xor(vs[i], off, 64);
  }
  const int wv = t >> 6;
  if ((t & 63) == 0) {
#pragma unroll
    for (int i = 0; i < MPB; ++i) part[i][wv] = vs[i];
  }
  __syncthreads();
  if (t < MPB) {
    values[mbase + t] = (part[t][0] + part[t][1]) + (part[t][2] + part[t][3]);
  }
}

extern "C" void kernel_launch(void* const* d_in, const int* in_sizes, int n_in,
                              void* d_out, int out_size, void* d_ws, size_t ws_size,
                              hipStream_t stream) {
  const float* points    = (const float*)d_in[0];
  const float* xyz       = (const float*)d_in[1];
  const float* scale_raw = (const float*)d_in[2];
  const float* rot_raw   = (const float*)d_in[3];
  const float* op_raw    = (const float*)d_in[4];
  const float* feat      = (const float*)d_in[5];

  float* values  = (float*)d_out;        // MM floats
  float* weights = (float*)d_out + MM;   // MM*NN floats

  gauss_fused<<<MM / MPB, THREADS, 0, stream>>>(
      points, xyz, scale_raw, rot_raw, op_raw, feat, values, weights);
}

// Round 7
// 43.754 us; speedup vs baseline: 1.0074x; 1.0074x over previous
//
#include <hip/hip_runtime.h>

// Gaussian3D, 2-kernel: values (M,1) + weights (M,N). M=8192, N=4096, F=1.
// d_out layout: [values (M) | weights (M*N)], float32.
//
// K1 (precomp): per gaussian, fold everything into 11 SoA coeffs of the
// expanded quadratic arg(p) = A:pp + B.p + C, weight = exp2(arg),
// A = k*Icov (k=-0.5*log2e, off-diag doubled), B = -2k*Icov*g,
// C = k*g'Icov*g + log2(sigmoid(op)), FF = feature. 180 KB, L2-resident.
//
// K2 (sweep): VALU-issue was the limiter (~1600 scalar inst/thread ~= 21 us
// ~= store drain). Pack row PAIRS into f32x2 so the 9-FMA quadratic chain and
// the vsum accumulate emit v_pk_fma_f32 (2 FMA/inst, VOP3P): ~half the issue
// slots. Coeffs stay scalar (splat operands). exp2 remains scalar v_exp_f32.
// 1024 blocks x 256 thr, 8 rows/block, 4 chunks x 4 consecutive n per thread.

#define THREADS 256
#define JPT 4
#define MPB 8
#define NN 4096
#define MM 8192
#define CHUNKS (NN / (THREADS * JPT))  // 4
#define NCOEF 11

typedef float f32x4 __attribute__((ext_vector_type(4)));
typedef float f32x2 __attribute__((ext_vector_type(2)));

// ---------------- kernel 1: fold per-gaussian coefficients ----------------
__global__ void gauss_precomp(const float* __restrict__ xyz,
                              const float* __restrict__ scale_raw,
                              const float* __restrict__ rot_raw,
                              const float* __restrict__ op_raw,
                              const float* __restrict__ feat,
                              float* __restrict__ C, int N) {
  const int n = blockIdx.x * blockDim.x + threadIdx.x;
  if (n >= N) return;
  const float k = -0.72134752044448170f;  // -0.5*log2(e)
  float qw = rot_raw[4*n+0], qx = rot_raw[4*n+1], qy = rot_raw[4*n+2], qz = rot_raw[4*n+3];
  const float inorm = rsqrtf(qw*qw + qx*qx + qy*qy + qz*qz);
  qw *= inorm; qx *= inorm; qy *= inorm; qz *= inorm;
  const float sx = __expf(scale_raw[3*n+0]);
  const float sy = __expf(scale_raw[3*n+1]);
  const float sz = __expf(scale_raw[3*n+2]);
  const float r00 = 1.f - 2.f*(qy*qy + qz*qz);
  const float r01 = 2.f*(qx*qy - qw*qz);
  const float r02 = 2.f*(qx*qz + qw*qy);
  const float r10 = 2.f*(qx*qy + qw*qz);
  const float r11 = 1.f - 2.f*(qx*qx + qz*qz);
  const float r12 = 2.f*(qy*qz - qw*qx);
  const float r20 = 2.f*(qx*qz - qw*qy);
  const float r21 = 2.f*(qy*qz + qw*qx);
  const float r22 = 1.f - 2.f*(qx*qx + qy*qy);
  const float a0 = r00*sx, a1 = r01*sy, a2 = r02*sz;
  const float b0 = r10*sx, b1 = r11*sy, b2 = r12*sz;
  const float c0 = r20*sx, c1 = r21*sy, c2 = r22*sz;
  const float c00 = a0*a0 + a1*a1 + a2*a2;
  const float c01 = a0*b0 + a1*b1 + a2*b2;
  const float c02 = a0*c0 + a1*c1 + a2*c2;
  const float c11 = b0*b0 + b1*b1 + b2*b2;
  const float c12 = b0*c0 + b1*c1 + b2*c2;
  const float c22 = c0*c0 + c1*c1 + c2*c2;
  const float m00 = c11*c22 - c12*c12;
  const float m01 = c02*c12 - c01*c22;
  const float m02 = c01*c12 - c02*c11;
  const float det = c00*m00 + c01*m01 + c02*m02;
  const float idet = 1.f / det;
  const float i00 = m00*idet;
  const float i01 = m01*idet;
  const float i02 = m02*idet;
  const float i11 = (c00*c22 - c02*c02)*idet;
  const float i12 = (c02*c01 - c00*c12)*idet;
  const float i22 = (c00*c11 - c01*c01)*idet;
  const float gx = xyz[3*n+0], gy = xyz[3*n+1], gz = xyz[3*n+2];
  const float w0 = i00*gx + i01*gy + i02*gz;
  const float w1 = i01*gx + i11*gy + i12*gz;
  const float w2 = i02*gx + i12*gy + i22*gz;
  const float gIg = gx*w0 + gy*w1 + gz*w2;
  const float lop = -__log2f(1.f + __expf(-op_raw[n]));  // log2(sigmoid)
  C[0*NN + n] = k * i00;          // A00
  C[1*NN + n] = k * i11;          // A11
  C[2*NN + n] = k * i22;          // A22
  C[3*NN + n] = 2.f * k * i01;    // A01
  C[4*NN + n] = 2.f * k * i02;    // A02
  C[5*NN + n] = 2.f * k * i12;    // A12
  C[6*NN + n] = -2.f * k * w0;    // B0
  C[7*NN + n] = -2.f * k * w1;    // B1
  C[8*NN + n] = -2.f * k * w2;    // B2
  C[9*NN + n] = k * gIg + lop;    // C
  C[10*NN + n] = feat[n];         // FF
}

// ---------------- kernel 2: M x N sweep (row-pair packed) ----------------
__global__ __launch_bounds__(THREADS, 4) void gauss_sweep(
    const float* __restrict__ points,
    const float* __restrict__ C,
    float* __restrict__ values,
    float* __restrict__ weights) {
  const int t = threadIdx.x;
  const int mbase = blockIdx.x * MPB;

  __shared__ float spts[MPB * 3];
  __shared__ float part[MPB][THREADS / 64];
  if (t < MPB * 3) spts[t] = points[mbase * 3 + t];
  __syncthreads();

  f32x2 vsp[MPB / 2];
#pragma unroll
  for (int p = 0; p < MPB / 2; ++p) vsp[p] = (f32x2){0.f, 0.f};

#pragma unroll
  for (int c = 0; c < CHUNKS; ++c) {
    const int n0 = c * (THREADS * JPT) + t * JPT;
    // 11 coalesced float4 coefficient loads (SoA, L2-resident)
    f32x4 A00 = *(const f32x4*)&C[0*NN + n0];
    f32x4 A11 = *(const f32x4*)&C[1*NN + n0];
    f32x4 A22 = *(const f32x4*)&C[2*NN + n0];
    f32x4 A01 = *(const f32x4*)&C[3*NN + n0];
    f32x4 A02 = *(const f32x4*)&C[4*NN + n0];
    f32x4 A12 = *(const f32x4*)&C[5*NN + n0];
    f32x4 B0  = *(const f32x4*)&C[6*NN + n0];
    f32x4 B1  = *(const f32x4*)&C[7*NN + n0];
    f32x4 B2  = *(const f32x4*)&C[8*NN + n0];
    f32x4 CC  = *(const f32x4*)&C[9*NN + n0];
    f32x4 FF  = *(const f32x4*)&C[10*NN + n0];

#pragma unroll
    for (int p = 0; p < MPB / 2; ++p) {
      // two rows packed: lanes {2p, 2p+1}
      const f32x2 px = {spts[6*p+0], spts[6*p+3]};
      const f32x2 py = {spts[6*p+1], spts[6*p+4]};
      const f32x2 pz = {spts[6*p+2], spts[6*p+5]};
      const f32x2 pxx = px*px, pyy = py*py, pzz = pz*pz;
      const f32x2 pxy = px*py, pxz = px*pz, pyz = py*pz;
      f32x4 wA, wB;
      f32x2 vacc = vsp[p];
#pragma unroll
      for (int j = 0; j < JPT; ++j) {
        f32x2 arg = {CC[j], CC[j]};
        arg += B2[j] * pz;      // v_pk_fma_f32 (scalar splat x vector)
        arg += B1[j] * py;
        arg += B0[j] * px;
        arg += A12[j] * pyz;
        arg += A02[j] * pxz;
        arg += A01[j] * pxy;
        arg += A22[j] * pzz;
        arg += A11[j] * pyy;
        arg += A00[j] * pxx;
        const float wa = __builtin_amdgcn_exp2f(arg.x);
        const float wb = __builtin_amdgcn_exp2f(arg.y);
        wA[j] = wa;
        wB[j] = wb;
        const f32x2 w2 = {wa, wb};
        vacc += w2 * FF[j];     // v_pk_fma_f32
      }
      vsp[p] = vacc;
      *(f32x4*)&weights[(size_t)(mbase + 2*p + 0) * NN + n0] = wA;
      *(f32x4*)&weights[(size_t)(mbase + 2*p + 1) * NN + n0] = wB;
    }
  }

  // batched wave reduction: MPB independent 6-stage chains
  float vs[MPB];
#pragma unroll
  for (int p = 0; p < MPB / 2; ++p) { vs[2*p] = vsp[p].x; vs[2*p+1] = vsp[p].y; }
#pragma unroll
  for (int i = 0; i < MPB; ++i) {
#pragma unroll
    for (int off = 32; off >= 1; off >>= 1)
      vs[i] += __shfl_xor(vs[i], off, 64);
  }
  const int wv = t >> 6;
  if ((t & 63) == 0) {
#pragma unroll
    for (int i = 0; i < MPB; ++i) part[i][wv] = vs[i];
  }
  __syncthreads();
  if (t < MPB) {
    values[mbase + t] = (part[t][0] + part[t][1]) + (part[t][2] + part[t][3]);
  }
}

extern "C" void kernel_launch(void* const* d_in, const int* in_sizes, int n_in,
                              void* d_out, int out_size, void* d_ws, size_t ws_size,
                              hipStream_t stream) {
  const float* points    = (const float*)d_in[0];
  const float* xyz       = (const float*)d_in[1];
  const float* scale_raw = (const float*)d_in[2];
  const float* rot_raw   = (const float*)d_in[3];
  const float* op_raw    = (const float*)d_in[4];
  const float* feat      = (const float*)d_in[5];

  float* values  = (float*)d_out;        // MM floats
  float* weights = (float*)d_out + MM;   // MM*NN floats
  float* C       = (float*)d_ws;         // NCOEF * NN floats = 180 KB

  gauss_precomp<<<(NN + THREADS - 1) / THREADS, THREADS, 0, stream>>>(
      xyz, scale_raw, rot_raw, op_raw, feat, C, NN);

  gauss_sweep<<<MM / MPB, THREADS, 0, stream>>>(points, C, values, weights);
}

// Round 8
// 38.474 us; speedup vs baseline: 1.1457x; 1.1372x over previous
//
#include <hip/hip_runtime.h>

// Gaussian3D, 2-kernel: values (M,1) + weights (M,N). M=8192, N=4096, F=1.
// d_out layout: [values (M) | weights (M*N)], float32.
//
// K1 (precomp): per gaussian, fold everything into 11 SoA coeffs of the
// expanded quadratic arg(p) = A:pp + B.p + C, weight = exp2(arg),
// A = k*Icov (k=-0.5*log2e, off-diag doubled), B = -2k*Icov*g,
// C = k*g'Icov*g + log2(sigmoid(op)), FF = feature. 180 KB, L2-resident.
//
// K2 (sweep): scalar FMA chain (9 fma + v_exp_f32 + fma per pair; CDNA4 has
// no double-rate packed fp32 -- round-7 lesson). Chunk loop kept DYNAMIC
// (#pragma unroll 1) so only one chunk's 44 coeff VGPRs are live at a time:
// bounded register pressure under launch_bounds(256,4), ~500-inst loop body
// (I-cache friendly), no spill risk. Weights stored nontemporal (streaming,
// never re-read).

#define THREADS 256
#define JPT 4
#define MPB 8
#define NN 4096
#define MM 8192
#define CHUNKS (NN / (THREADS * JPT))  // 4
#define NCOEF 11

typedef float f32x4 __attribute__((ext_vector_type(4)));

// ---------------- kernel 1: fold per-gaussian coefficients ----------------
__global__ void gauss_precomp(const float* __restrict__ xyz,
                              const float* __restrict__ scale_raw,
                              const float* __restrict__ rot_raw,
                              const float* __restrict__ op_raw,
                              const float* __restrict__ feat,
                              float* __restrict__ C, int N) {
  const int n = blockIdx.x * blockDim.x + threadIdx.x;
  if (n >= N) return;
  const float k = -0.72134752044448170f;  // -0.5*log2(e)
  float qw = rot_raw[4*n+0], qx = rot_raw[4*n+1], qy = rot_raw[4*n+2], qz = rot_raw[4*n+3];
  const float inorm = rsqrtf(qw*qw + qx*qx + qy*qy + qz*qz);
  qw *= inorm; qx *= inorm; qy *= inorm; qz *= inorm;
  const float sx = __expf(scale_raw[3*n+0]);
  const float sy = __expf(scale_raw[3*n+1]);
  const float sz = __expf(scale_raw[3*n+2]);
  const float r00 = 1.f - 2.f*(qy*qy + qz*qz);
  const float r01 = 2.f*(qx*qy - qw*qz);
  const float r02 = 2.f*(qx*qz + qw*qy);
  const float r10 = 2.f*(qx*qy + qw*qz);
  const float r11 = 1.f - 2.f*(qx*qx + qz*qz);
  const float r12 = 2.f*(qy*qz - qw*qx);
  const float r20 = 2.f*(qx*qz - qw*qy);
  const float r21 = 2.f*(qy*qz + qw*qx);
  const float r22 = 1.f - 2.f*(qx*qx + qy*qy);
  const float a0 = r00*sx, a1 = r01*sy, a2 = r02*sz;
  const float b0 = r10*sx, b1 = r11*sy, b2 = r12*sz;
  const float c0 = r20*sx, c1 = r21*sy, c2 = r22*sz;
  const float c00 = a0*a0 + a1*a1 + a2*a2;
  const float c01 = a0*b0 + a1*b1 + a2*b2;
  const float c02 = a0*c0 + a1*c1 + a2*c2;
  const float c11 = b0*b0 + b1*b1 + b2*b2;
  const float c12 = b0*c0 + b1*c1 + b2*c2;
  const float c22 = c0*c0 + c1*c1 + c2*c2;
  const float m00 = c11*c22 - c12*c12;
  const float m01 = c02*c12 - c01*c22;
  const float m02 = c01*c12 - c02*c11;
  const float det = c00*m00 + c01*m01 + c02*m02;
  const float idet = 1.f / det;
  const float i00 = m00*idet;
  const float i01 = m01*idet;
  const float i02 = m02*idet;
  const float i11 = (c00*c22 - c02*c02)*idet;
  const float i12 = (c02*c01 - c00*c12)*idet;
  const float i22 = (c00*c11 - c01*c01)*idet;
  const float gx = xyz[3*n+0], gy = xyz[3*n+1], gz = xyz[3*n+2];
  const float w0 = i00*gx + i01*gy + i02*gz;
  const float w1 = i01*gx + i11*gy + i12*gz;
  const float w2 = i02*gx + i12*gy + i22*gz;
  const float gIg = gx*w0 + gy*w1 + gz*w2;
  const float lop = -__log2f(1.f + __expf(-op_raw[n]));  // log2(sigmoid)
  C[0*NN + n] = k * i00;          // A00
  C[1*NN + n] = k * i11;          // A11
  C[2*NN + n] = k * i22;          // A22
  C[3*NN + n] = 2.f * k * i01;    // A01
  C[4*NN + n] = 2.f * k * i02;    // A02
  C[5*NN + n] = 2.f * k * i12;    // A12
  C[6*NN + n] = -2.f * k * w0;    // B0
  C[7*NN + n] = -2.f * k * w1;    // B1
  C[8*NN + n] = -2.f * k * w2;    // B2
  C[9*NN + n] = k * gIg + lop;    // C
  C[10*NN + n] = feat[n];         // FF
}

// ---------------- kernel 2: M x N sweep ----------------
__global__ __launch_bounds__(THREADS, 4) void gauss_sweep(
    const float* __restrict__ points,
    const float* __restrict__ C,
    float* __restrict__ values,
    float* __restrict__ weights) {
  const int t = threadIdx.x;
  const int mbase = blockIdx.x * MPB;

  __shared__ float spts[MPB * 3];
  __shared__ float part[MPB][THREADS / 64];
  if (t < MPB * 3) spts[t] = points[mbase * 3 + t];
  __syncthreads();

  float vs[MPB];
#pragma unroll
  for (int i = 0; i < MPB; ++i) vs[i] = 0.f;

#pragma unroll 1
  for (int c = 0; c < CHUNKS; ++c) {
    const int n0 = c * (THREADS * JPT) + t * JPT;
    // 11 coalesced float4 coefficient loads (SoA, L2-resident)
    f32x4 A00 = *(const f32x4*)&C[0*NN + n0];
    f32x4 A11 = *(const f32x4*)&C[1*NN + n0];
    f32x4 A22 = *(const f32x4*)&C[2*NN + n0];
    f32x4 A01 = *(const f32x4*)&C[3*NN + n0];
    f32x4 A02 = *(const f32x4*)&C[4*NN + n0];
    f32x4 A12 = *(const f32x4*)&C[5*NN + n0];
    f32x4 B0  = *(const f32x4*)&C[6*NN + n0];
    f32x4 B1  = *(const f32x4*)&C[7*NN + n0];
    f32x4 B2  = *(const f32x4*)&C[8*NN + n0];
    f32x4 CC  = *(const f32x4*)&C[9*NN + n0];
    f32x4 FF  = *(const f32x4*)&C[10*NN + n0];

#pragma unroll
    for (int i = 0; i < MPB; ++i) {
      const float px = spts[3*i+0];
      const float py = spts[3*i+1];
      const float pz = spts[3*i+2];
      const float pxx = px*px, pyy = py*py, pzz = pz*pz;
      const float pxy = px*py, pxz = px*pz, pyz = py*pz;
      f32x4 w;
      float vsum = vs[i];
#pragma unroll
      for (int j = 0; j < JPT; ++j) {
        float arg = CC[j];
        arg = fmaf(B2[j], pz, arg);
        arg = fmaf(B1[j], py, arg);
        arg = fmaf(B0[j], px, arg);
        arg = fmaf(A12[j], pyz, arg);
        arg = fmaf(A02[j], pxz, arg);
        arg = fmaf(A01[j], pxy, arg);
        arg = fmaf(A22[j], pzz, arg);
        arg = fmaf(A11[j], pyy, arg);
        arg = fmaf(A00[j], pxx, arg);
        const float wj = __builtin_amdgcn_exp2f(arg);
        w[j] = wj;
        vsum = fmaf(wj, FF[j], vsum);
      }
      vs[i] = vsum;
      __builtin_nontemporal_store(
          w, (f32x4*)&weights[(size_t)(mbase + i) * NN + n0]);
    }
  }

  // batched wave reduction: MPB independent 6-stage chains
#pragma unroll
  for (int i = 0; i < MPB; ++i) {
#pragma unroll
    for (int off = 32; off >= 1; off >>= 1)
      vs[i] += __shfl_xor(vs[i], off, 64);
  }
  const int wv = t >> 6;
  if ((t & 63) == 0) {
#pragma unroll
    for (int i = 0; i < MPB; ++i) part[i][wv] = vs[i];
  }
  __syncthreads();
  if (t < MPB) {
    values[mbase + t] = (part[t][0] + part[t][1]) + (part[t][2] + part[t][3]);
  }
}

extern "C" void kernel_launch(void* const* d_in, const int* in_sizes, int n_in,
                              void* d_out, int out_size, void* d_ws, size_t ws_size,
                              hipStream_t stream) {
  const float* points    = (const float*)d_in[0];
  const float* xyz       = (const float*)d_in[1];
  const float* scale_raw = (const float*)d_in[2];
  const float* rot_raw   = (const float*)d_in[3];
  const float* op_raw    = (const float*)d_in[4];
  const float* feat      = (const float*)d_in[5];

  float* values  = (float*)d_out;        // MM floats
  float* weights = (float*)d_out + MM;   // MM*NN floats
  float* C       = (float*)d_ws;         // NCOEF * NN floats = 180 KB

  gauss_precomp<<<(NN + THREADS - 1) / THREADS, THREADS, 0, stream>>>(
      xyz, scale_raw, rot_raw, op_raw, feat, C, NN);

  gauss_sweep<<<MM / MPB, THREADS, 0, stream>>>(points, C, values, weights);
}

// Round 9
// 33.248 us; speedup vs baseline: 1.3258x; 1.1572x over previous
//
#include <hip/hip_runtime.h>

// Gaussian3D, 2-kernel: values (M,1) + weights (M,N). M=8192, N=4096, F=1.
// d_out layout: [values (M) | weights (M*N)], float32.
//
// K1 (precomp): per gaussian, fold everything into 11 SoA coeffs of the
// expanded quadratic arg(p) = A:pp + B.p + C, weight = exp2(arg),
// A = k*Icov (k=-0.5*log2e, off-diag doubled), B = -2k*Icov*g,
// C = k*g'Icov*g + log2(sigmoid(op)), FF = feature. 180 KB, L2-resident.
//
// K2 (sweep): R5 structure (best: 33.4 us), single change: MPB 8 -> 16.
// Full unroll on the chunk loop (R8 lesson: unroll 1 kills the compiler's
// cross-chunk software pipelining, +5 us). Plain f32x4 stores (nt ~neutral).
// 512 blocks x 256 thr, 16 rows/block, 4 chunks x 4 consecutive n/thread:
// halves coeff reload traffic, doubles store-burst run per coeff phase.

#define THREADS 256
#define JPT 4
#define MPB 16
#define NN 4096
#define MM 8192
#define CHUNKS (NN / (THREADS * JPT))  // 4
#define NCOEF 11

typedef float f32x4 __attribute__((ext_vector_type(4)));

// ---------------- kernel 1: fold per-gaussian coefficients ----------------
__global__ void gauss_precomp(const float* __restrict__ xyz,
                              const float* __restrict__ scale_raw,
                              const float* __restrict__ rot_raw,
                              const float* __restrict__ op_raw,
                              const float* __restrict__ feat,
                              float* __restrict__ C, int N) {
  const int n = blockIdx.x * blockDim.x + threadIdx.x;
  if (n >= N) return;
  const float k = -0.72134752044448170f;  // -0.5*log2(e)
  float qw = rot_raw[4*n+0], qx = rot_raw[4*n+1], qy = rot_raw[4*n+2], qz = rot_raw[4*n+3];
  const float inorm = rsqrtf(qw*qw + qx*qx + qy*qy + qz*qz);
  qw *= inorm; qx *= inorm; qy *= inorm; qz *= inorm;
  const float sx = __expf(scale_raw[3*n+0]);
  const float sy = __expf(scale_raw[3*n+1]);
  const float sz = __expf(scale_raw[3*n+2]);
  const float r00 = 1.f - 2.f*(qy*qy + qz*qz);
  const float r01 = 2.f*(qx*qy - qw*qz);
  const float r02 = 2.f*(qx*qz + qw*qy);
  const float r10 = 2.f*(qx*qy + qw*qz);
  const float r11 = 1.f - 2.f*(qx*qx + qz*qz);
  const float r12 = 2.f*(qy*qz - qw*qx);
  const float r20 = 2.f*(qx*qz - qw*qy);
  const float r21 = 2.f*(qy*qz + qw*qx);
  const float r22 = 1.f - 2.f*(qx*qx + qy*qy);
  const float a0 = r00*sx, a1 = r01*sy, a2 = r02*sz;
  const float b0 = r10*sx, b1 = r11*sy, b2 = r12*sz;
  const float c0 = r20*sx, c1 = r21*sy, c2 = r22*sz;
  const float c00 = a0*a0 + a1*a1 + a2*a2;
  const float c01 = a0*b0 + a1*b1 + a2*b2;
  const float c02 = a0*c0 + a1*c1 + a2*c2;
  const float c11 = b0*b0 + b1*b1 + b2*b2;
  const float c12 = b0*c0 + b1*c1 + b2*c2;
  const float c22 = c0*c0 + c1*c1 + c2*c2;
  const float m00 = c11*c22 - c12*c12;
  const float m01 = c02*c12 - c01*c22;
  const float m02 = c01*c12 - c02*c11;
  const float det = c00*m00 + c01*m01 + c02*m02;
  const float idet = 1.f / det;
  const float i00 = m00*idet;
  const float i01 = m01*idet;
  const float i02 = m02*idet;
  const float i11 = (c00*c22 - c02*c02)*idet;
  const float i12 = (c02*c01 - c00*c12)*idet;
  const float i22 = (c00*c11 - c01*c01)*idet;
  const float gx = xyz[3*n+0], gy = xyz[3*n+1], gz = xyz[3*n+2];
  const float w0 = i00*gx + i01*gy + i02*gz;
  const float w1 = i01*gx + i11*gy + i12*gz;
  const float w2 = i02*gx + i12*gy + i22*gz;
  const float gIg = gx*w0 + gy*w1 + gz*w2;
  const float lop = -__log2f(1.f + __expf(-op_raw[n]));  // log2(sigmoid)
  C[0*NN + n] = k * i00;          // A00
  C[1*NN + n] = k * i11;          // A11
  C[2*NN + n] = k * i22;          // A22
  C[3*NN + n] = 2.f * k * i01;    // A01
  C[4*NN + n] = 2.f * k * i02;    // A02
  C[5*NN + n] = 2.f * k * i12;    // A12
  C[6*NN + n] = -2.f * k * w0;    // B0
  C[7*NN + n] = -2.f * k * w1;    // B1
  C[8*NN + n] = -2.f * k * w2;    // B2
  C[9*NN + n] = k * gIg + lop;    // C
  C[10*NN + n] = feat[n];         // FF
}

// ---------------- kernel 2: M x N sweep ----------------
__global__ __launch_bounds__(THREADS, 4) void gauss_sweep(
    const float* __restrict__ points,
    const float* __restrict__ C,
    float* __restrict__ values,
    float* __restrict__ weights) {
  const int t = threadIdx.x;
  const int mbase = blockIdx.x * MPB;

  __shared__ float spts[MPB * 3];
  __shared__ float part[MPB][THREADS / 64];
  if (t < MPB * 3) spts[t] = points[mbase * 3 + t];
  __syncthreads();

  float vs[MPB];
#pragma unroll
  for (int i = 0; i < MPB; ++i) vs[i] = 0.f;

#pragma unroll
  for (int c = 0; c < CHUNKS; ++c) {
    const int n0 = c * (THREADS * JPT) + t * JPT;
    // 11 coalesced float4 coefficient loads (SoA, L2-resident)
    f32x4 A00 = *(const f32x4*)&C[0*NN + n0];
    f32x4 A11 = *(const f32x4*)&C[1*NN + n0];
    f32x4 A22 = *(const f32x4*)&C[2*NN + n0];
    f32x4 A01 = *(const f32x4*)&C[3*NN + n0];
    f32x4 A02 = *(const f32x4*)&C[4*NN + n0];
    f32x4 A12 = *(const f32x4*)&C[5*NN + n0];
    f32x4 B0  = *(const f32x4*)&C[6*NN + n0];
    f32x4 B1  = *(const f32x4*)&C[7*NN + n0];
    f32x4 B2  = *(const f32x4*)&C[8*NN + n0];
    f32x4 CC  = *(const f32x4*)&C[9*NN + n0];
    f32x4 FF  = *(const f32x4*)&C[10*NN + n0];

#pragma unroll
    for (int i = 0; i < MPB; ++i) {
      const float px = spts[3*i+0];
      const float py = spts[3*i+1];
      const float pz = spts[3*i+2];
      const float pxx = px*px, pyy = py*py, pzz = pz*pz;
      const float pxy = px*py, pxz = px*pz, pyz = py*pz;
      f32x4 w;
      float vsum = vs[i];
#pragma unroll
      for (int j = 0; j < JPT; ++j) {
        float arg = CC[j];
        arg = fmaf(B2[j], pz, arg);
        arg = fmaf(B1[j], py, arg);
        arg = fmaf(B0[j], px, arg);
        arg = fmaf(A12[j], pyz, arg);
        arg = fmaf(A02[j], pxz, arg);
        arg = fmaf(A01[j], pxy, arg);
        arg = fmaf(A22[j], pzz, arg);
        arg = fmaf(A11[j], pyy, arg);
        arg = fmaf(A00[j], pxx, arg);
        const float wj = __builtin_amdgcn_exp2f(arg);
        w[j] = wj;
        vsum = fmaf(wj, FF[j], vsum);
      }
      vs[i] = vsum;
      *(f32x4*)&weights[(size_t)(mbase + i) * NN + n0] = w;
    }
  }

  // batched wave reduction: MPB independent 6-stage chains
#pragma unroll
  for (int i = 0; i < MPB; ++i) {
#pragma unroll
    for (int off = 32; off >= 1; off >>= 1)
      vs[i] += __shfl_xor(vs[i], off, 64);
  }
  const int wv = t >> 6;
  if ((t & 63) == 0) {
#pragma unroll
    for (int i = 0; i < MPB; ++i) part[i][wv] = vs[i];
  }
  __syncthreads();
  if (t < MPB) {
    values[mbase + t] = (part[t][0] + part[t][1]) + (part[t][2] + part[t][3]);
  }
}

extern "C" void kernel_launch(void* const* d_in, const int* in_sizes, int n_in,
                              void* d_out, int out_size, void* d_ws, size_t ws_size,
                              hipStream_t stream) {
  const float* points    = (const float*)d_in[0];
  const float* xyz       = (const float*)d_in[1];
  const float* scale_raw = (const float*)d_in[2];
  const float* rot_raw   = (const float*)d_in[3];
  const float* op_raw    = (const float*)d_in[4];
  const float* feat      = (const float*)d_in[5];

  float* values  = (float*)d_out;        // MM floats
  float* weights = (float*)d_out + MM;   // MM*NN floats
  float* C       = (float*)d_ws;         // NCOEF * NN floats = 180 KB

  gauss_precomp<<<(NN + THREADS - 1) / THREADS, THREADS, 0, stream>>>(
      xyz, scale_raw, rot_raw, op_raw, feat, C, NN);

  gauss_sweep<<<MM / MPB, THREADS, 0, stream>>>(points, C, values, weights);
}

// Round 10
// 33.012 us; speedup vs baseline: 1.3352x; 1.0072x over previous
//
#include <hip/hip_runtime.h>

// Gaussian3D, 2-kernel: values (M,1) + weights (M,N). M=8192, N=4096, F=1.
// d_out layout: [values (M) | weights (M*N)], float32.
//
// K1 (precomp): per gaussian, fold everything into 11 SoA coeffs of the
// expanded quadratic arg(p) = A:pp + B.p + C, weight = exp2(arg),
// A = k*Icov (k=-0.5*log2e, off-diag doubled), B = -2k*Icov*g,
// C = k*g'Icov*g + log2(sigmoid(op)), FF = feature. 180 KB, L2-resident.
//
// K2 (sweep): R9 structure (best: 33.2 us), single change: DE-LOCKSTEP the
// write pattern. All blocks previously executed the same (chunk, row)
// schedule, so the instantaneous channel-selecting address bits (12..17,
// from chunk*4KB + row*16KB) were identical chip-wide -- potential HBM
// channel aliasing that no occupancy/nt/order lever touches. Rotate chunk
// order by (blockIdx&3) and row order by ((blockIdx>>2)&15): instantaneous
// coverage spans all of bits 12-17. Uniform (SGPR) rotation, unroll kept.

#define THREADS 256
#define JPT 4
#define MPB 16
#define NN 4096
#define MM 8192
#define CHUNKS (NN / (THREADS * JPT))  // 4
#define NCOEF 11

typedef float f32x4 __attribute__((ext_vector_type(4)));

// ---------------- kernel 1: fold per-gaussian coefficients ----------------
__global__ void gauss_precomp(const float* __restrict__ xyz,
                              const float* __restrict__ scale_raw,
                              const float* __restrict__ rot_raw,
                              const float* __restrict__ op_raw,
                              const float* __restrict__ feat,
                              float* __restrict__ C, int N) {
  const int n = blockIdx.x * blockDim.x + threadIdx.x;
  if (n >= N) return;
  const float k = -0.72134752044448170f;  // -0.5*log2(e)
  float qw = rot_raw[4*n+0], qx = rot_raw[4*n+1], qy = rot_raw[4*n+2], qz = rot_raw[4*n+3];
  const float inorm = rsqrtf(qw*qw + qx*qx + qy*qy + qz*qz);
  qw *= inorm; qx *= inorm; qy *= inorm; qz *= inorm;
  const float sx = __expf(scale_raw[3*n+0]);
  const float sy = __expf(scale_raw[3*n+1]);
  const float sz = __expf(scale_raw[3*n+2]);
  const float r00 = 1.f - 2.f*(qy*qy + qz*qz);
  const float r01 = 2.f*(qx*qy - qw*qz);
  const float r02 = 2.f*(qx*qz + qw*qy);
  const float r10 = 2.f*(qx*qy + qw*qz);
  const float r11 = 1.f - 2.f*(qx*qx + qz*qz);
  const float r12 = 2.f*(qy*qz - qw*qx);
  const float r20 = 2.f*(qx*qz - qw*qy);
  const float r21 = 2.f*(qy*qz + qw*qx);
  const float r22 = 1.f - 2.f*(qx*qx + qy*qy);
  const float a0 = r00*sx, a1 = r01*sy, a2 = r02*sz;
  const float b0 = r10*sx, b1 = r11*sy, b2 = r12*sz;
  const float c0 = r20*sx, c1 = r21*sy, c2 = r22*sz;
  const float c00 = a0*a0 + a1*a1 + a2*a2;
  const float c01 = a0*b0 + a1*b1 + a2*b2;
  const float c02 = a0*c0 + a1*c1 + a2*c2;
  const float c11 = b0*b0 + b1*b1 + b2*b2;
  const float c12 = b0*c0 + b1*c1 + b2*c2;
  const float c22 = c0*c0 + c1*c1 + c2*c2;
  const float m00 = c11*c22 - c12*c12;
  const float m01 = c02*c12 - c01*c22;
  const float m02 = c01*c12 - c02*c11;
  const float det = c00*m00 + c01*m01 + c02*m02;
  const float idet = 1.f / det;
  const float i00 = m00*idet;
  const float i01 = m01*idet;
  const float i02 = m02*idet;
  const float i11 = (c00*c22 - c02*c02)*idet;
  const float i12 = (c02*c01 - c00*c12)*idet;
  const float i22 = (c00*c11 - c01*c01)*idet;
  const float gx = xyz[3*n+0], gy = xyz[3*n+1], gz = xyz[3*n+2];
  const float w0 = i00*gx + i01*gy + i02*gz;
  const float w1 = i01*gx + i11*gy + i12*gz;
  const float w2 = i02*gx + i12*gy + i22*gz;
  const float gIg = gx*w0 + gy*w1 + gz*w2;
  const float lop = -__log2f(1.f + __expf(-op_raw[n]));  // log2(sigmoid)
  C[0*NN + n] = k * i00;          // A00
  C[1*NN + n] = k * i11;          // A11
  C[2*NN + n] = k * i22;          // A22
  C[3*NN + n] = 2.f * k * i01;    // A01
  C[4*NN + n] = 2.f * k * i02;    // A02
  C[5*NN + n] = 2.f * k * i12;    // A12
  C[6*NN + n] = -2.f * k * w0;    // B0
  C[7*NN + n] = -2.f * k * w1;    // B1
  C[8*NN + n] = -2.f * k * w2;    // B2
  C[9*NN + n] = k * gIg + lop;    // C
  C[10*NN + n] = feat[n];         // FF
}

// ---------------- kernel 2: M x N sweep ----------------
__global__ __launch_bounds__(THREADS, 4) void gauss_sweep(
    const float* __restrict__ points,
    const float* __restrict__ C,
    float* __restrict__ values,
    float* __restrict__ weights) {
  const int t = threadIdx.x;
  const int mbase = blockIdx.x * MPB;
  const int crot = blockIdx.x & (CHUNKS - 1);        // chunk rotation
  const int irot = (blockIdx.x >> 2) & (MPB - 1);    // row rotation

  __shared__ float spts[MPB * 3];
  __shared__ float part[MPB][THREADS / 64];
  if (t < MPB * 3) spts[t] = points[mbase * 3 + t];
  __syncthreads();

  float vs[MPB];
#pragma unroll
  for (int i = 0; i < MPB; ++i) vs[i] = 0.f;

#pragma unroll
  for (int cc = 0; cc < CHUNKS; ++cc) {
    const int c = (cc + crot) & (CHUNKS - 1);
    const int n0 = c * (THREADS * JPT) + t * JPT;
    // 11 coalesced float4 coefficient loads (SoA, L2-resident)
    f32x4 A00 = *(const f32x4*)&C[0*NN + n0];
    f32x4 A11 = *(const f32x4*)&C[1*NN + n0];
    f32x4 A22 = *(const f32x4*)&C[2*NN + n0];
    f32x4 A01 = *(const f32x4*)&C[3*NN + n0];
    f32x4 A02 = *(const f32x4*)&C[4*NN + n0];
    f32x4 A12 = *(const f32x4*)&C[5*NN + n0];
    f32x4 B0  = *(const f32x4*)&C[6*NN + n0];
    f32x4 B1  = *(const f32x4*)&C[7*NN + n0];
    f32x4 B2  = *(const f32x4*)&C[8*NN + n0];
    f32x4 CC  = *(const f32x4*)&C[9*NN + n0];
    f32x4 FF  = *(const f32x4*)&C[10*NN + n0];

#pragma unroll
    for (int ii = 0; ii < MPB; ++ii) {
      const int i = (ii + irot) & (MPB - 1);
      const float px = spts[3*i+0];
      const float py = spts[3*i+1];
      const float pz = spts[3*i+2];
      const float pxx = px*px, pyy = py*py, pzz = pz*pz;
      const float pxy = px*py, pxz = px*pz, pyz = py*pz;
      f32x4 w;
      float vsum = vs[i];
#pragma unroll
      for (int j = 0; j < JPT; ++j) {
        float arg = CC[j];
        arg = fmaf(B2[j], pz, arg);
        arg = fmaf(B1[j], py, arg);
        arg = fmaf(B0[j], px, arg);
        arg = fmaf(A12[j], pyz, arg);
        arg = fmaf(A02[j], pxz, arg);
        arg = fmaf(A01[j], pxy, arg);
        arg = fmaf(A22[j], pzz, arg);
        arg = fmaf(A11[j], pyy, arg);
        arg = fmaf(A00[j], pxx, arg);
        const float wj = __builtin_amdgcn_exp2f(arg);
        w[j] = wj;
        vsum = fmaf(wj, FF[j], vsum);
      }
      vs[i] = vsum;
      *(f32x4*)&weights[(size_t)(mbase + i) * NN + n0] = w;
    }
  }

  // batched wave reduction: MPB independent 6-stage chains
#pragma unroll
  for (int i = 0; i < MPB; ++i) {
#pragma unroll
    for (int off = 32; off >= 1; off >>= 1)
      vs[i] += __shfl_xor(vs[i], off, 64);
  }
  const int wv = t >> 6;
  if ((t & 63) == 0) {
#pragma unroll
    for (int i = 0; i < MPB; ++i) part[i][wv] = vs[i];
  }
  __syncthreads();
  if (t < MPB) {
    values[mbase + t] = (part[t][0] + part[t][1]) + (part[t][2] + part[t][3]);
  }
}

extern "C" void kernel_launch(void* const* d_in, const int* in_sizes, int n_in,
                              void* d_out, int out_size, void* d_ws, size_t ws_size,
                              hipStream_t stream) {
  const float* points    = (const float*)d_in[0];
  const float* xyz       = (const float*)d_in[1];
  const float* scale_raw = (const float*)d_in[2];
  const float* rot_raw   = (const float*)d_in[3];
  const float* op_raw    = (const float*)d_in[4];
  const float* feat      = (const float*)d_in[5];

  float* values  = (float*)d_out;        // MM floats
  float* weights = (float*)d_out + MM;   // MM*NN floats
  float* C       = (float*)d_ws;         // NCOEF * NN floats = 180 KB

  gauss_precomp<<<(NN + THREADS - 1) / THREADS, THREADS, 0, stream>>>(
      xyz, scale_raw, rot_raw, op_raw, feat, C, NN);

  gauss_sweep<<<MM / MPB, THREADS, 0, stream>>>(points, C, values, weights);
}